// Round 1
// baseline (1577.991 us; speedup 1.0000x reference)
//
#include <hip/hip_runtime.h>
#include <hip/hip_bf16.h>
#include <math.h>

// PPO fused loss, fp32 baseline.
// T=262144, S=128, H=1024, A=16.
// Pipeline:
//   init_acc      : zero ws accumulators
//   scan_pass1/2/3: segmented affine scan for masked discounted returns,
//                   adv = ret - values stored to ws, sum/sumsq accumulated
//   stats_kernel  : mean, 1/(std(ddof=1)+1e-7)
//   main_kernel   : per 16-row tile: h=tanh(states@W1+b1) (LDS),
//                   mu/lv heads, log-probs, ratio, clipped actor term -> atomic
//   finalize      : out = critic + actor
// ws usage: ~1.1 MB of float scratch (see offsets below).

#define T_TOTAL 262144
#define S_DIM 128
#define H_DIM 1024
#define A_DIM 16
#define GAMMA 0.99f
#define SEG_LEN 64
#define NSEG 4096      // T_TOTAL / SEG_LEN
#define GRP 16
#define NGRP 256       // NSEG / GRP

// ws float offsets
#define WS_SUM   0
#define WS_SUMSQ 1
#define WS_MEAN  2
#define WS_ISTD  3
#define WS_TERM  4
#define WS_SEGA  8
#define WS_SEGB  (WS_SEGA + NSEG)
#define WS_INC   (WS_SEGB + NSEG)
#define WS_ADV   (WS_INC + NSEG)   // + T_TOTAL floats

__device__ __forceinline__ float fast_tanh(float x) {
  // 1 - 2/(exp(2x)+1); saturates correctly at +/-inf
  float e = __expf(2.0f * x);
  return 1.0f - 2.0f / (e + 1.0f);
}

__global__ void init_acc(float* ws) {
  if (threadIdx.x < 8) ws[threadIdx.x] = 0.0f;
}

// Each thread computes its segment's affine aggregate (A,B):
// ret_at_seg_start = B + A * ret_entering_from_right
__global__ void scan_pass1(const float* __restrict__ rewards,
                           const int* __restrict__ masks,
                           float* __restrict__ ws) {
  int g = blockIdx.x * blockDim.x + threadIdx.x;  // 0..NSEG-1
  int lo = g * SEG_LEN;
  float a = 1.0f, b = 0.0f;
  for (int i = lo + SEG_LEN - 1; i >= lo; --i) {
    float gi = GAMMA * (float)masks[i];
    b = rewards[i] + gi * b;
    a = gi * a;
  }
  ws[WS_SEGA + g] = a;
  ws[WS_SEGB + g] = b;
}

// Single block: hierarchical suffix scan of segment aggregates ->
// incoming return value for every segment.
__global__ void scan_pass2(float* __restrict__ ws) {
  __shared__ float gA[NGRP], gB[NGRP], ginc[NGRP];
  int t = threadIdx.x;  // 0..255
  int lo = t * GRP, hi = lo + GRP - 1;
  float A = 1.0f, B = 0.0f;
  for (int s = hi; s >= lo; --s) {
    float as = ws[WS_SEGA + s], bs = ws[WS_SEGB + s];
    B = bs + as * B;
    A = as * A;
  }
  gA[t] = A; gB[t] = B;
  __syncthreads();
  if (t == 0) {
    float x = 0.0f;
    ginc[NGRP - 1] = 0.0f;
    for (int g = NGRP - 1; g >= 1; --g) {
      x = gB[g] + gA[g] * x;
      ginc[g - 1] = x;
    }
  }
  __syncthreads();
  float x = ginc[t];
  for (int s = hi; s >= lo; --s) {
    ws[WS_INC + s] = x;
    x = ws[WS_SEGB + s] + ws[WS_SEGA + s] * x;
  }
}

// Replay each segment with its true incoming value; emit adv, accumulate sums.
__global__ void scan_pass3(const float* __restrict__ rewards,
                           const int* __restrict__ masks,
                           const float* __restrict__ values,
                           float* __restrict__ ws) {
  int g = blockIdx.x * blockDim.x + threadIdx.x;
  int lo = g * SEG_LEN;
  float x = ws[WS_INC + g];
  float s1 = 0.0f, s2 = 0.0f;
  for (int i = lo + SEG_LEN - 1; i >= lo; --i) {
    float gi = GAMMA * (float)masks[i];
    x = rewards[i] + gi * x;
    float adv = x - values[i];
    ws[WS_ADV + i] = adv;
    s1 += adv;
    s2 += adv * adv;
  }
  for (int m = 1; m < 64; m <<= 1) {
    s1 += __shfl_xor(s1, m);
    s2 += __shfl_xor(s2, m);
  }
  if ((threadIdx.x & 63) == 0) {
    atomicAdd(&ws[WS_SUM], s1);
    atomicAdd(&ws[WS_SUMSQ], s2);
  }
}

__global__ void stats_kernel(float* ws) {
  if (threadIdx.x == 0) {
    float s1 = ws[WS_SUM], s2 = ws[WS_SUMSQ];
    float n = (float)T_TOTAL;
    float mean = s1 / n;
    float var = (s2 - s1 * s1 / n) / (n - 1.0f);
    var = fmaxf(var, 0.0f);
    ws[WS_MEAN] = mean;
    ws[WS_ISTD] = 1.0f / (sqrtf(var) + 1e-7f);
  }
}

// One block per 16-row tile. 256 threads.
// LDS: lds_h is a union: states tile (16x128) during phase 1, then h (16x1024).
__launch_bounds__(256, 2)
__global__ void main_kernel(const float* __restrict__ states,
                            const float* __restrict__ actions,
                            const float* __restrict__ beta,
                            const float* __restrict__ W1,
                            const float* __restrict__ b1,
                            const float* __restrict__ W_mu,
                            const float* __restrict__ b_mu,
                            const float* __restrict__ W_lv,
                            const float* __restrict__ b_lv,
                            float* __restrict__ ws) {
  __shared__ float lds_h[16 * H_DIM];       // 64 KB (union with states tile)
  __shared__ float lds_red[4 * 32 * 17];    // cross-wave reduce, pad 17 vs banks
  __shared__ float lds_term[16];

  const int tid = threadIdx.x;
  const int t0 = blockIdx.x * 16;

  // Stage 16 states rows (2048 floats) coalesced.
  {
    const float4* src = (const float4*)(states + (size_t)t0 * S_DIM);
    float4* dst = (float4*)lds_h;
    dst[tid] = src[tid];
    dst[tid + 256] = src[tid + 256];
  }
  __syncthreads();

  // Phase 1: each thread owns 4 H-columns for all 16 rows.
  float4 acc[16];
#pragma unroll
  for (int r = 0; r < 16; ++r) acc[r] = make_float4(0.f, 0.f, 0.f, 0.f);
  const int c0 = tid * 4;
  for (int k4 = 0; k4 < S_DIM; k4 += 4) {
    float4 w0 = *(const float4*)(W1 + (size_t)(k4 + 0) * H_DIM + c0);
    float4 w1 = *(const float4*)(W1 + (size_t)(k4 + 1) * H_DIM + c0);
    float4 w2 = *(const float4*)(W1 + (size_t)(k4 + 2) * H_DIM + c0);
    float4 w3 = *(const float4*)(W1 + (size_t)(k4 + 3) * H_DIM + c0);
#pragma unroll
    for (int r = 0; r < 16; ++r) {
      float4 s = *(const float4*)(lds_h + r * S_DIM + k4);  // broadcast
      acc[r].x += s.x * w0.x + s.y * w1.x + s.z * w2.x + s.w * w3.x;
      acc[r].y += s.x * w0.y + s.y * w1.y + s.z * w2.y + s.w * w3.y;
      acc[r].z += s.x * w0.z + s.y * w1.z + s.z * w2.z + s.w * w3.z;
      acc[r].w += s.x * w0.w + s.y * w1.w + s.z * w2.w + s.w * w3.w;
    }
  }
  float4 bb = *(const float4*)(b1 + c0);
  __syncthreads();  // everyone done reading states region
#pragma unroll
  for (int r = 0; r < 16; ++r) {
    float4 v;
    v.x = fast_tanh(acc[r].x + bb.x);
    v.y = fast_tanh(acc[r].y + bb.y);
    v.z = fast_tanh(acc[r].z + bb.z);
    v.w = fast_tanh(acc[r].w + bb.w);
    *(float4*)(lds_h + r * H_DIM + c0) = v;
  }
  __syncthreads();

  // Phase 2: 32 output cols (16 mu + 16 lv), 8 k-partitions of 128.
  const int col = tid & 31;
  const int part = tid >> 5;
  const float* Wc = (col < 16) ? (W_mu + col) : (W_lv + (col - 16));
  float a2[16];
#pragma unroll
  for (int r = 0; r < 16; ++r) a2[r] = 0.0f;
  const int kbase = part * 128;
  for (int k4 = 0; k4 < 128; k4 += 4) {
    int k = kbase + k4;
    float w0 = Wc[(size_t)(k + 0) * A_DIM];
    float w1 = Wc[(size_t)(k + 1) * A_DIM];
    float w2 = Wc[(size_t)(k + 2) * A_DIM];
    float w3 = Wc[(size_t)(k + 3) * A_DIM];
#pragma unroll
    for (int r = 0; r < 16; ++r) {
      float4 h4 = *(const float4*)(lds_h + r * H_DIM + k);
      a2[r] += h4.x * w0 + h4.y * w1 + h4.z * w2 + h4.w * w3;
    }
  }
  // pair-reduce parts (p, p+1) within wave
#pragma unroll
  for (int r = 0; r < 16; ++r) a2[r] += __shfl_xor(a2[r], 32);
  if ((tid & 32) == 0) {
    int w = tid >> 6;      // wave 0..3
    int c = tid & 31;
#pragma unroll
    for (int r = 0; r < 16; ++r) lds_red[(w * 32 + c) * 17 + r] = a2[r];
  }
  __syncthreads();

  // Final: thread (r=tid>>4, j=tid&15) owns (row r, action j).
  const int r = tid >> 4;
  const int j = tid & 15;
  float mu = 0.0f, lv = 0.0f;
#pragma unroll
  for (int w = 0; w < 4; ++w) {
    mu += lds_red[(w * 32 + j) * 17 + r];
    lv += lds_red[(w * 32 + 16 + j) * 17 + r];
  }
  mu += b_mu[j];
  lv += b_lv[j];
  const int t = t0 + r;
  float act = actions[(size_t)t * A_DIM + j];
  float blp = beta[(size_t)t * A_DIM + j];
  float sd = __expf(0.5f * lv);
  float z = (act - mu) / sd;
  float d = -0.5f * z * z - 0.5f * lv - 0.91893853320467274f - blp;
  d += __shfl_xor(d, 1);
  d += __shfl_xor(d, 2);
  d += __shfl_xor(d, 4);
  d += __shfl_xor(d, 8);
  if (j == 0) {
    float ratio = __expf(d);
    float mean = ws[WS_MEAN], istd = ws[WS_ISTD];
    float ah = (ws[WS_ADV + t] - mean) * istd;
    float rc = fminf(fmaxf(ratio, 0.8f), 1.2f);
    lds_term[r] = fminf(ratio * ah, rc * ah);
  }
  __syncthreads();
  if (tid == 0) {
    float s = 0.0f;
#pragma unroll
    for (int rr = 0; rr < 16; ++rr) s += lds_term[rr];
    atomicAdd(&ws[WS_TERM], s);
  }
}

__global__ void finalize(const float* __restrict__ ws, float* __restrict__ out) {
  if (threadIdx.x == 0) {
    float n = (float)T_TOTAL;
    out[0] = ws[WS_SUMSQ] / n - ws[WS_TERM] / n;  // critic + actor
  }
}

extern "C" void kernel_launch(void* const* d_in, const int* in_sizes, int n_in,
                              void* d_out, int out_size, void* d_ws, size_t ws_size,
                              hipStream_t stream) {
  const float* states  = (const float*)d_in[0];
  const float* actions = (const float*)d_in[1];
  const float* rewards = (const float*)d_in[2];
  const float* values  = (const float*)d_in[3];
  const float* beta    = (const float*)d_in[4];
  const float* W1      = (const float*)d_in[5];
  const float* b1      = (const float*)d_in[6];
  const float* W_mu    = (const float*)d_in[7];
  const float* b_mu    = (const float*)d_in[8];
  const float* W_lv    = (const float*)d_in[9];
  const float* b_lv    = (const float*)d_in[10];
  const int*   masks   = (const int*)d_in[11];
  float* ws = (float*)d_ws;
  float* out = (float*)d_out;

  hipLaunchKernelGGL(init_acc, dim3(1), dim3(64), 0, stream, ws);
  hipLaunchKernelGGL(scan_pass1, dim3(NSEG / 256), dim3(256), 0, stream, rewards, masks, ws);
  hipLaunchKernelGGL(scan_pass2, dim3(1), dim3(NGRP), 0, stream, ws);
  hipLaunchKernelGGL(scan_pass3, dim3(NSEG / 256), dim3(256), 0, stream, rewards, masks, values, ws);
  hipLaunchKernelGGL(stats_kernel, dim3(1), dim3(64), 0, stream, ws);
  hipLaunchKernelGGL(main_kernel, dim3(T_TOTAL / 16), dim3(256), 0, stream,
                     states, actions, beta, W1, b1, W_mu, b_mu, W_lv, b_lv, ws);
  hipLaunchKernelGGL(finalize, dim3(1), dim3(64), 0, stream, ws, out);
}

// Round 2
// 422.711 us; speedup vs baseline: 3.7330x; 3.7330x over previous
//
#include <hip/hip_runtime.h>
#include <math.h>

// PPO fused loss, round 2: bf16 MFMA for both GEMMs.
// T=262144, S=128, H=1024, A=16.
//   prep_w1f / prep_whf : convert W1 / (W_mu|W_lv) fp32 -> bf16 in MFMA
//                         B-fragment order (lane-contiguous 16B per frag)
//   scan_pass1/2/3      : segmented affine scan for returns; adv -> ws
//   stats_kernel        : mean, 1/(std+1e-7)
//   main2               : 64 rows/block. GEMM1 (states@W1, MFMA 16x16x32)
//                         -> tanh -> per-wave LDS transpose -> GEMM2 heads
//                         (K split over waves) -> cross-wave reduce ->
//                         log-probs/ratio/clip epilogue -> atomic
//   finalize            : out = critic + actor

typedef __attribute__((ext_vector_type(8))) short short8_t;
typedef __attribute__((ext_vector_type(4))) short short4_t;
typedef __attribute__((ext_vector_type(4))) float float4_t;
typedef __attribute__((ext_vector_type(2))) float float2_t;

#define T_TOTAL 262144
#define S_DIM 128
#define H_DIM 1024
#define A_DIM 16
#define GAMMA 0.99f
#define SEG_LEN 64
#define NSEG 4096
#define GRP 16
#define NGRP 256

// ws float offsets
#define WS_SUM   0
#define WS_SUMSQ 1
#define WS_MEAN  2
#define WS_ISTD  3
#define WS_TERM  4
#define WS_SEGA  8
#define WS_SEGB  (WS_SEGA + NSEG)
#define WS_INC   (WS_SEGB + NSEG)
#define WS_ADV   (WS_INC + NSEG)            // + T_TOTAL floats
#define WS_W1F   (WS_ADV + T_TOTAL)         // 131072 bf16 = 65536 floats
#define WS_WHF   (WS_W1F + 65536)           // 32768 bf16 = 16384 floats

// LDS layout (bytes) for main2
#define SM_A    0          // 16384 B : A fragments (64x128 bf16, frag order)
#define SM_H    16384      // 4 waves x 8704 B : per-wave h buf / C2 partials
#define SM_TERM 51200      // 4 floats
#define SM_SIZE 51232

__device__ __forceinline__ short f2bf(float f) {
  unsigned u = __float_as_uint(f);
  u += 0x7fffu + ((u >> 16) & 1u);
  return (short)(u >> 16);
}

__device__ __forceinline__ float fast_tanh(float x) {
  float e = __expf(2.0f * x);
  return 1.0f - __fdividef(2.0f, e + 1.0f);
}

__global__ void init_acc(float* ws) {
  if (threadIdx.x < 8) ws[threadIdx.x] = 0.0f;
}

// W1[128x1024] fp32 -> bf16 B-frags: [ntile(64)][kf(4)][lane(64)][e(8)]
// element = W1[(kf*32 + (lane>>4)*8 + e)][ntile*16 + (lane&15)]
__global__ void prep_w1f(const float* __restrict__ W1, short* __restrict__ w1f) {
  int id = blockIdx.x * 256 + threadIdx.x;   // 0..16383
  int lane = id & 63;
  int kf = (id >> 6) & 3;
  int nt = id >> 8;
  int quad = lane >> 4, col = nt * 16 + (lane & 15);
  int kbase = kf * 32 + quad * 8;
#pragma unroll
  for (int e = 0; e < 8; ++e)
    w1f[(size_t)id * 8 + e] = f2bf(W1[(size_t)(kbase + e) * H_DIM + col]);
}

// W_mu|W_lv [1024x16] -> bf16 B-frags: [nt(2)][kf(32)][lane(64)][e(8)]
__global__ void prep_whf(const float* __restrict__ W_mu,
                         const float* __restrict__ W_lv,
                         short* __restrict__ whf) {
  int id = blockIdx.x * 256 + threadIdx.x;   // 0..4095
  int lane = id & 63;
  int kf = (id >> 6) & 31;
  int nt = id >> 11;
  const float* src = nt ? W_lv : W_mu;
  int quad = lane >> 4, col = lane & 15;
  int kbase = kf * 32 + quad * 8;
#pragma unroll
  for (int e = 0; e < 8; ++e)
    whf[(size_t)id * 8 + e] = f2bf(src[(size_t)(kbase + e) * A_DIM + col]);
}

__global__ void scan_pass1(const float* __restrict__ rewards,
                           const int* __restrict__ masks,
                           float* __restrict__ ws) {
  int g = blockIdx.x * blockDim.x + threadIdx.x;
  int lo = g * SEG_LEN;
  float a = 1.0f, b = 0.0f;
  for (int i = lo + SEG_LEN - 1; i >= lo; --i) {
    float gi = GAMMA * (float)masks[i];
    b = rewards[i] + gi * b;
    a = gi * a;
  }
  ws[WS_SEGA + g] = a;
  ws[WS_SEGB + g] = b;
}

__global__ void scan_pass2(float* __restrict__ ws) {
  __shared__ float gA[NGRP], gB[NGRP], ginc[NGRP];
  int t = threadIdx.x;
  int lo = t * GRP, hi = lo + GRP - 1;
  float A = 1.0f, B = 0.0f;
  for (int s = hi; s >= lo; --s) {
    float as = ws[WS_SEGA + s], bs = ws[WS_SEGB + s];
    B = bs + as * B;
    A = as * A;
  }
  gA[t] = A; gB[t] = B;
  __syncthreads();
  if (t == 0) {
    float x = 0.0f;
    ginc[NGRP - 1] = 0.0f;
    for (int g = NGRP - 1; g >= 1; --g) {
      x = gB[g] + gA[g] * x;
      ginc[g - 1] = x;
    }
  }
  __syncthreads();
  float x = ginc[t];
  for (int s = hi; s >= lo; --s) {
    ws[WS_INC + s] = x;
    x = ws[WS_SEGB + s] + ws[WS_SEGA + s] * x;
  }
}

__global__ void scan_pass3(const float* __restrict__ rewards,
                           const int* __restrict__ masks,
                           const float* __restrict__ values,
                           float* __restrict__ ws) {
  int g = blockIdx.x * blockDim.x + threadIdx.x;
  int lo = g * SEG_LEN;
  float x = ws[WS_INC + g];
  float s1 = 0.0f, s2 = 0.0f;
  for (int i = lo + SEG_LEN - 1; i >= lo; --i) {
    float gi = GAMMA * (float)masks[i];
    x = rewards[i] + gi * x;
    float adv = x - values[i];
    ws[WS_ADV + i] = adv;
    s1 += adv;
    s2 += adv * adv;
  }
  for (int m = 1; m < 64; m <<= 1) {
    s1 += __shfl_xor(s1, m);
    s2 += __shfl_xor(s2, m);
  }
  if ((threadIdx.x & 63) == 0) {
    atomicAdd(&ws[WS_SUM], s1);
    atomicAdd(&ws[WS_SUMSQ], s2);
  }
}

__global__ void stats_kernel(float* ws) {
  if (threadIdx.x == 0) {
    float s1 = ws[WS_SUM], s2 = ws[WS_SUMSQ];
    float n = (float)T_TOTAL;
    float mean = s1 / n;
    float var = (s2 - s1 * s1 / n) / (n - 1.0f);
    var = fmaxf(var, 0.0f);
    ws[WS_MEAN] = mean;
    ws[WS_ISTD] = 1.0f / (sqrtf(var) + 1e-7f);
  }
}

// 64 rows per block, 256 threads (4 waves). Wave w owns GEMM1 cols
// [w*256,(w+1)*256) == GEMM2 K-range; cross-wave reduce for heads.
__launch_bounds__(256, 2)
__global__ void main2(const float* __restrict__ states,
                      const float* __restrict__ actions,
                      const float* __restrict__ beta,
                      const float* __restrict__ b1g,
                      const float* __restrict__ bmug,
                      const float* __restrict__ blvg,
                      const short* __restrict__ W1f,
                      const short* __restrict__ Whf,
                      float* __restrict__ ws) {
  __shared__ __align__(16) unsigned char smem[SM_SIZE];
  short* Ab = (short*)(smem + SM_A);
  float* lds_term = (float*)(smem + SM_TERM);

  const int tid = threadIdx.x;
  const int lane = tid & 63;
  const int w = tid >> 6;
  const int quad = lane >> 4;
  const int acol = lane & 15;
  const int t0 = blockIdx.x * 64;
  float* hw = (float*)(smem + SM_H) + w * 2176;   // 64 x 34 fp32, per-wave

  // ---- stage states (64x128 fp32) -> bf16 A-fragments in LDS ----
  {
    const float4* src = (const float4*)(states + (size_t)t0 * S_DIM);
#pragma unroll
    for (int i = 0; i < 8; ++i) {
      int f = tid + i * 256;
      float4 v = src[f];
      int row = f >> 5, kq = f & 31;
      int rt = row >> 4, rr = row & 15;
      int k = kq * 4, kf = k >> 5, qd = (k >> 3) & 3, j0 = k & 7;
      short4_t pk;
      pk[0] = f2bf(v.x); pk[1] = f2bf(v.y); pk[2] = f2bf(v.z); pk[3] = f2bf(v.w);
      *(short4_t*)(Ab + (((rt * 4 + kf) * 64 + qd * 16 + rr) << 3) + j0) = pk;
    }
  }
  __syncthreads();

  // A fragments -> registers (shared by all waves)
  short8_t a1[4][4];
#pragma unroll
  for (int rt = 0; rt < 4; ++rt)
#pragma unroll
    for (int kf = 0; kf < 4; ++kf)
      a1[rt][kf] = *((const short8_t*)Ab + (rt * 4 + kf) * 64 + lane);

  float4_t acc2[4][2];
#pragma unroll
  for (int rt = 0; rt < 4; ++rt)
#pragma unroll
    for (int nt = 0; nt < 2; ++nt)
      acc2[rt][nt] = (float4_t){0.f, 0.f, 0.f, 0.f};

  const int nbase = w * 16;
  for (int kk = 0; kk < 8; ++kk) {
    // ---- GEMM1: two 16-col chunks -> tanh -> per-wave LDS h buf ----
#pragma unroll
    for (int c = 0; c < 2; ++c) {
      int nt1 = nbase + kk * 2 + c;
      const short8_t* bp = (const short8_t*)W1f + nt1 * 4 * 64 + lane;
      short8_t bf0 = bp[0], bf1 = bp[64], bf2 = bp[128], bf3 = bp[192];
      float b1v = b1g[nt1 * 16 + acol];
#pragma unroll
      for (int rt = 0; rt < 4; ++rt) {
        float4_t acc = (float4_t){0.f, 0.f, 0.f, 0.f};
        acc = __builtin_amdgcn_mfma_f32_16x16x32_bf16(a1[rt][0], bf0, acc, 0, 0, 0);
        acc = __builtin_amdgcn_mfma_f32_16x16x32_bf16(a1[rt][1], bf1, acc, 0, 0, 0);
        acc = __builtin_amdgcn_mfma_f32_16x16x32_bf16(a1[rt][2], bf2, acc, 0, 0, 0);
        acc = __builtin_amdgcn_mfma_f32_16x16x32_bf16(a1[rt][3], bf3, acc, 0, 0, 0);
        float* hp = hw + (rt * 16 + quad * 4) * 34 + c * 16 + acol;
        hp[0]   = fast_tanh(acc[0] + b1v);
        hp[34]  = fast_tanh(acc[1] + b1v);
        hp[68]  = fast_tanh(acc[2] + b1v);
        hp[102] = fast_tanh(acc[3] + b1v);
      }
    }
    __syncthreads();   // intra-wave LDS transpose ordering (cheap, safe)

    // ---- h chunk (64x32) -> A2 fragments -> GEMM2 into acc2 ----
    int kf2 = w * 8 + kk;
    const short8_t* b2p = (const short8_t*)Whf + kf2 * 64 + lane;
    short8_t b2mu = b2p[0];
    short8_t b2lv = b2p[32 * 64];
#pragma unroll
    for (int rt = 0; rt < 4; ++rt) {
      const float* hp = hw + (rt * 16 + acol) * 34 + quad * 8;
      float2_t x0 = *(const float2_t*)hp;
      float2_t x1 = *(const float2_t*)(hp + 2);
      float2_t x2 = *(const float2_t*)(hp + 4);
      float2_t x3 = *(const float2_t*)(hp + 6);
      short8_t a2;
      a2[0] = f2bf(x0[0]); a2[1] = f2bf(x0[1]);
      a2[2] = f2bf(x1[0]); a2[3] = f2bf(x1[1]);
      a2[4] = f2bf(x2[0]); a2[5] = f2bf(x2[1]);
      a2[6] = f2bf(x3[0]); a2[7] = f2bf(x3[1]);
      acc2[rt][0] = __builtin_amdgcn_mfma_f32_16x16x32_bf16(a2, b2mu, acc2[rt][0], 0, 0, 0);
      acc2[rt][1] = __builtin_amdgcn_mfma_f32_16x16x32_bf16(a2, b2lv, acc2[rt][1], 0, 0, 0);
    }
    __syncthreads();   // WAR: next iter rewrites hw
  }

  // ---- cross-wave reduce of head partials (reuse own h region) ----
  float* redw = hw;
#pragma unroll
  for (int rt = 0; rt < 4; ++rt)
#pragma unroll
    for (int nt = 0; nt < 2; ++nt)
      *(float4_t*)(redw + ((rt * 2 + nt) * 64 + lane) * 4) = acc2[rt][nt];
  __syncthreads();

  // ---- epilogue: mu/lv -> log-probs -> ratio -> clipped actor term ----
  const float mean = ws[WS_MEAN], istd = ws[WS_ISTD];
  const float* redbase = (const float*)(smem + SM_H);
  const int j = tid & 15;
  const int rsub = tid >> 4;
  float bmu = bmug[j], blv = blvg[j];
  float term = 0.0f;
#pragma unroll
  for (int p = 0; p < 4; ++p) {
    int m = p * 16 + rsub;
    int q2 = (m & 15) >> 2, reg = m & 3;
    float mu = bmu, lv = blv;
#pragma unroll
    for (int wv = 0; wv < 4; ++wv) {
      const float* rw = redbase + wv * 2176;
      mu += rw[((p * 2 + 0) * 64 + q2 * 16 + j) * 4 + reg];
      lv += rw[((p * 2 + 1) * 64 + q2 * 16 + j) * 4 + reg];
    }
    int t = t0 + m;
    float act = actions[(size_t)t * A_DIM + j];
    float blp = beta[(size_t)t * A_DIM + j];
    float isd = __expf(-0.5f * lv);
    float z = (act - mu) * isd;
    float d = -0.5f * z * z - 0.5f * lv - 0.9189385332046727f - blp;
    d += __shfl_xor(d, 1);
    d += __shfl_xor(d, 2);
    d += __shfl_xor(d, 4);
    d += __shfl_xor(d, 8);
    if (j == 0) {
      float ratio = __expf(d);
      float ah = (ws[WS_ADV + t] - mean) * istd;
      float rc = fminf(fmaxf(ratio, 0.8f), 1.2f);
      term += fminf(ratio * ah, rc * ah);
    }
  }
#pragma unroll
  for (int m2 = 1; m2 < 64; m2 <<= 1) term += __shfl_xor(term, m2);
  if (lane == 0) lds_term[w] = term;
  __syncthreads();
  if (tid == 0)
    atomicAdd(&ws[WS_TERM], lds_term[0] + lds_term[1] + lds_term[2] + lds_term[3]);
}

__global__ void finalize(const float* __restrict__ ws, float* __restrict__ out) {
  if (threadIdx.x == 0) {
    float n = (float)T_TOTAL;
    out[0] = ws[WS_SUMSQ] / n - ws[WS_TERM] / n;
  }
}

extern "C" void kernel_launch(void* const* d_in, const int* in_sizes, int n_in,
                              void* d_out, int out_size, void* d_ws, size_t ws_size,
                              hipStream_t stream) {
  const float* states  = (const float*)d_in[0];
  const float* actions = (const float*)d_in[1];
  const float* rewards = (const float*)d_in[2];
  const float* values  = (const float*)d_in[3];
  const float* beta    = (const float*)d_in[4];
  const float* W1      = (const float*)d_in[5];
  const float* b1      = (const float*)d_in[6];
  const float* W_mu    = (const float*)d_in[7];
  const float* b_mu    = (const float*)d_in[8];
  const float* W_lv    = (const float*)d_in[9];
  const float* b_lv    = (const float*)d_in[10];
  const int*   masks   = (const int*)d_in[11];
  float* ws = (float*)d_ws;
  float* out = (float*)d_out;
  short* w1f = (short*)(ws + WS_W1F);
  short* whf = (short*)(ws + WS_WHF);

  hipLaunchKernelGGL(init_acc, dim3(1), dim3(64), 0, stream, ws);
  hipLaunchKernelGGL(prep_w1f, dim3(64), dim3(256), 0, stream, W1, w1f);
  hipLaunchKernelGGL(prep_whf, dim3(16), dim3(256), 0, stream, W_mu, W_lv, whf);
  hipLaunchKernelGGL(scan_pass1, dim3(NSEG / 256), dim3(256), 0, stream, rewards, masks, ws);
  hipLaunchKernelGGL(scan_pass2, dim3(1), dim3(NGRP), 0, stream, ws);
  hipLaunchKernelGGL(scan_pass3, dim3(NSEG / 256), dim3(256), 0, stream, rewards, masks, values, ws);
  hipLaunchKernelGGL(stats_kernel, dim3(1), dim3(64), 0, stream, ws);
  hipLaunchKernelGGL(main2, dim3(T_TOTAL / 64), dim3(256), 0, stream,
                     states, actions, beta, b1, b_mu, b_lv, w1f, whf, ws);
  hipLaunchKernelGGL(finalize, dim3(1), dim3(64), 0, stream, ws, out);
}